// Round 9
// baseline (291.982 us; speedup 1.0000x reference)
//
#include <hip/hip_runtime.h>
#include <hip/hip_bf16.h>

// Round 17: TLP 16 -> 24 waves/CU (the only lever that has moved wall time:
// R8's 8->16 waves gave the first real win).
//   - 64x256 tile, BK=32: buffers 20KB, dbuf 40KB, launch_bounds(512,6)
//     -> 3 blocks/CU = 24 waves/CU
//   - 64B LDS rows: wave64 ds_read_b128 is UNIFORM 8 words/bank = structural
//     minimum -> XOR swizzle dropped, staging is plain linear gload_lds
//   - waves 0-3 stage 1A+2B (vmcnt(3)), waves 4-7 stage 2B (vmcnt(2))
//   - accumulation order unchanged (k=0,32,... per output) -> same absmax
//   - pack_all / attn_fused / epilogue verbatim from passing R8

#define B_SZ     4096
#define LSTM_N   400
#define NG       1600   // 4*LSTM
#define VOCAB    73
#define NATTN    10
#define CHARLEN  64
#define KP1      512
#define KP23     896

typedef _Float16 half8 __attribute__((ext_vector_type(8)));
typedef __attribute__((ext_vector_type(4))) float floatx4;

__device__ __forceinline__ void gload_lds16(const void* g, void* l) {
    __builtin_amdgcn_global_load_lds(
        (const __attribute__((address_space(1))) void*)g,
        (__attribute__((address_space(3))) void*)l, 16, 0, 0);
}

// ---------------------------------------------------------------- pack (all)
// Layouts:
//   X1 (KP1):  [w_prev 0..73 | inputs 73..76 | h1 76..476 | 0pad]
//   XA (KP1):  [h1n 0..400 | w_prev 400..473 | inputs 473..476 | 0pad]
//   X2 (KP23): [h1n 0..400 | inputs 400..403 | w 403..476 | h2 476..876 | 0pad]
//   X3 (KP23): [h2n 0..400 | inputs 400..403 | w 403..476 | h3 476..876 | 0pad]
// W rows: n = 4u+g <- src row g*400+u.
#define CW1   102400            // 1600 * 64
#define CW23  179200            // 1600 * 112
#define CWA   4096              // 64 * 64
#define CX1   262144            // 4096 * 64
#define CXA   57344             // 4096 * 14   (cols 400..512)
#define CX23  253952            // 4096 * 62   (cols 400..896, both X2 & X3)
#define O1    (CW1)
#define O2    (O1 + CW23)
#define O3    (O2 + CW23)
#define O4    (O3 + CWA)
#define O5    (O4 + CX1)
#define O6    (O5 + CXA)
#define O7    (O6 + CX23)       // 1038336 = 256 * 4056

__global__ __launch_bounds__(256) void pack_all(const float* __restrict__ Wih1,
                                                const float* __restrict__ Whh1,
                                                const float* __restrict__ Wih2,
                                                const float* __restrict__ Whh2,
                                                const float* __restrict__ Wih3,
                                                const float* __restrict__ Whh3,
                                                const float* __restrict__ W_attn,
                                                const float* __restrict__ w_prev,
                                                const float* __restrict__ inputs,
                                                const float* __restrict__ h1,
                                                const float* __restrict__ h2,
                                                const float* __restrict__ h3,
                                                _Float16* __restrict__ W1,
                                                _Float16* __restrict__ W2,
                                                _Float16* __restrict__ W3,
                                                _Float16* __restrict__ Wa,
                                                _Float16* __restrict__ X1,
                                                _Float16* __restrict__ XA,
                                                _Float16* __restrict__ X2,
                                                _Float16* __restrict__ X3)
{
    const int id = blockIdx.x * 256 + threadIdx.x;
    half8 hv;

    if (id < O1) {                       // ---- W1: 1600 x 512
        const int row = id >> 6;
        const int k0  = (id & 63) << 3;
        const int u = row >> 2, g = row & 3;
        const int src = g * 400 + u;
#pragma unroll
        for (int e = 0; e < 8; e++) {
            const int k = k0 + e;
            float x = 0.f;
            if (k < 76)           x = Wih1[(size_t)src * 76 + k];
            else if (k < 476)     x = Whh1[(size_t)src * 400 + (k - 76)];
            hv[e] = (_Float16)x;
        }
        *(half8*)(W1 + (size_t)row * KP1 + k0) = hv;
    } else if (id < O3) {                // ---- W2 / W3: 1600 x 896
        const int id2 = id - O1;
        const bool is3 = (id2 >= CW23);
        const int id3 = is3 ? id2 - CW23 : id2;
        const int row = id3 / 112;
        const int k0  = (id3 - row * 112) << 3;
        const int u = row >> 2, g = row & 3;
        const int src = g * 400 + u;
        const float* Wih = is3 ? Wih3 : Wih2;
        const float* Whh = is3 ? Whh3 : Whh2;
#pragma unroll
        for (int e = 0; e < 8; e++) {
            const int k = k0 + e;
            float x = 0.f;
            if (k < 400)          x = Wih[(size_t)src * 476 + 3 + k];
            else if (k < 403)     x = Wih[(size_t)src * 476 + (k - 400)];
            else if (k < 476)     x = Wih[(size_t)src * 476 + k];
            else if (k < 876)     x = Whh[(size_t)src * 400 + (k - 476)];
            hv[e] = (_Float16)x;
        }
        *(half8*)((is3 ? W3 : W2) + (size_t)row * KP23 + k0) = hv;
    } else if (id < O4) {                // ---- Wa: 64 x 512 (rows >=30 zero)
        const int id4 = id - O3;
        const int row = id4 >> 6;
        const int k0  = (id4 & 63) << 3;
#pragma unroll
        for (int e = 0; e < 8; e++) {
            const int k = k0 + e;
            float x = 0.f;
            if (row < 30) {
                if (k < 400)      x = W_attn[(size_t)row * 476 + 76 + k];
                else if (k < 473) x = W_attn[(size_t)row * 476 + (k - 400)];
                else if (k < 476) x = W_attn[(size_t)row * 476 + 73 + (k - 473)];
            }
            hv[e] = (_Float16)x;
        }
        *(half8*)(Wa + (size_t)row * KP1 + k0) = hv;
    } else if (id < O5) {                // ---- X1: 4096 x 512
        const int id5 = id - O4;
        const int b  = id5 >> 6;
        const int k0 = (id5 & 63) << 3;
#pragma unroll
        for (int e = 0; e < 8; e++) {
            const int k = k0 + e;
            float x = 0.f;
            if (k < 73)           x = w_prev[(size_t)b * 73 + k];
            else if (k < 76)      x = inputs[(size_t)b * 3 + (k - 73)];
            else if (k < 476)     x = h1[(size_t)b * 400 + (k - 76)];
            hv[e] = (_Float16)x;
        }
        *(half8*)(X1 + (size_t)b * KP1 + k0) = hv;
    } else if (id < O6) {                // ---- XA cols 400..512
        const int id6 = id - O5;
        const int b  = id6 / 14;
        const int k0 = 400 + ((id6 - b * 14) << 3);
#pragma unroll
        for (int e = 0; e < 8; e++) {
            const int k = k0 + e;
            float x = 0.f;
            if (k < 473)          x = w_prev[(size_t)b * 73 + (k - 400)];
            else if (k < 476)     x = inputs[(size_t)b * 3 + (k - 473)];
            hv[e] = (_Float16)x;
        }
        *(half8*)(XA + (size_t)b * KP1 + k0) = hv;
    } else if (id < O7) {                // ---- X2+X3 cols 400..896
        const int id7 = id - O6;
        const int b  = id7 / 62;
        const int k0 = 400 + ((id7 - b * 62) << 3);
        half8 h2v, h3v;
#pragma unroll
        for (int e = 0; e < 8; e++) {
            const int k = k0 + e;
            float x2 = 0.f, x3 = 0.f;
            if (k < 403)                    { x2 = inputs[(size_t)b * 3 + (k - 400)]; x3 = x2; }
            else if (k >= 476 && k < 876)   { x2 = h2[(size_t)b * 400 + (k - 476)];
                                              x3 = h3[(size_t)b * 400 + (k - 476)]; }
            h2v[e] = (_Float16)x2;
            h3v[e] = (_Float16)x3;
        }
        *(half8*)(X2 + (size_t)b * KP23 + k0) = h2v;
        *(half8*)(X3 + (size_t)b * KP23 + k0) = h3v;
    }
}

// ---------------------------------------------------------------- fused GEMM
// 64(rows) x 256(batch) tile, BK=32, 512 thr = 8 waves (2m x 4n), each wave
// 32x64 = 2x4 frags, 8 MFMAs/K-step. Dbuf 2x20KB = 40KB -> 3 blocks/CU =
// 24 waves/CU. 64B LDS rows (A rows 0..63, B rows 64..319): wave64
// ds_read_b128 lands uniformly 8 words/bank = structural minimum, no swizzle.
template<int KP>
__global__ __launch_bounds__(512, 6) void gemm_fused_t(const _Float16* __restrict__ Wm,
                                                       const _Float16* __restrict__ X,
                                                       const float* __restrict__ bias,
                                                       const float* __restrict__ c_in,
                                                       _Float16* __restrict__ d1, int ld1,
                                                       _Float16* __restrict__ d2, int ld2,
                                                       float* __restrict__ fout)
{
    __shared__ _Float16 lds[2][320 * 32];   // [A 64 rows | B 256 rows] x 32 halves

    const int t    = threadIdx.x;
    const int w    = t >> 6;                // 0..7
    const int lane = t & 63;
    const int quad = lane >> 4;
    const int l16  = lane & 15;
    // bijective XCD chunks: 400 = 8 x 50; each XCD: 2 batch-tiles x 25 rows
    const int fid  = blockIdx.y * 16 + blockIdx.x;
    const int xcd  = fid & 7;
    const int loc  = fid >> 3;              // 0..49
    const int bx   = xcd * 2 + loc / 25;    // batch tile 0..15
    const int by   = loc % 25;              // row tile 0..24
    const int m0   = by * 64;
    const int n0   = bx * 256;
    const int wm   = (w >> 2) * 32;         // 0 or 32
    const int wn   = (w & 3) * 64;          // 0..192
    const int lrow = lane >> 2;             // 0..15 row-in-16 for staging
    const int lgr  = lane & 3;              // granule 0..3 (16B) within 64B row

    floatx4 acc[2][4] = {};

    // staging (linear, no swizzle): A = 256 granules (waves 0-3, 1 each),
    // B = 1024 granules (all 8 waves, 2 each). gload_lds dest = uniform
    // base + lane*16.
    auto stageB = [&](int sb, int k0) {
#pragma unroll
        for (int j = 0; j < 2; j++)
            gload_lds16(X + (size_t)(n0 + w * 32 + j * 16 + lrow) * KP + k0 + lgr * 8,
                        &lds[sb][(64 + w * 32 + j * 16) * 32]);
    };
    auto stageA = [&](int sb, int k0) {
        gload_lds16(Wm + (size_t)(m0 + w * 16 + lrow) * KP + k0 + lgr * 8,
                    &lds[sb][(w * 16) * 32]);
    };

    if (w < 4) { stageA(0, 0); }
    stageB(0, 0);
    constexpr int NT = KP / 32;
#pragma unroll
    for (int kt = 0; kt < NT; kt++) {
        const int sb = kt & 1;
        if (kt + 1 < NT) {
            if (w < 4) {                      // 3 loads in flight
                stageA(sb ^ 1, (kt + 1) * 32);
                stageB(sb ^ 1, (kt + 1) * 32);
                asm volatile("s_waitcnt vmcnt(3)" ::: "memory");
            } else {                          // 2 loads in flight
                stageB(sb ^ 1, (kt + 1) * 32);
                asm volatile("s_waitcnt vmcnt(2)" ::: "memory");
            }
        } else {
            asm volatile("s_waitcnt vmcnt(0)" ::: "memory");
        }
        __builtin_amdgcn_s_barrier();
        __builtin_amdgcn_sched_barrier(0);

        {
            half8 af[2], bf[4];
#pragma unroll
            for (int i = 0; i < 2; i++)
                af[i] = *(const half8*)(&lds[sb][(wm + i * 16 + l16) * 32 + quad * 8]);
#pragma unroll
            for (int i = 0; i < 4; i++)
                bf[i] = *(const half8*)(&lds[sb][(64 + wn + i * 16 + l16) * 32 + quad * 8]);
            __builtin_amdgcn_s_setprio(1);
#pragma unroll
            for (int mt = 0; mt < 2; mt++)
#pragma unroll
                for (int nt = 0; nt < 4; nt++)
                    acc[mt][nt] = __builtin_amdgcn_mfma_f32_16x16x32_f16(
                        af[mt], bf[nt], acc[mt][nt], 0, 0, 0);
            __builtin_amdgcn_s_setprio(0);
        }
        __builtin_amdgcn_s_barrier();
    }
    __builtin_amdgcn_sched_barrier(0);

    // ---------------- epilogue: descattered I/O via LDS transpose ----------
    const int u0 = m0 >> 2;                   // first unit of this block (x16)
    float*    Cs   = (float*)&lds[0][0];      // [256][20] f32 (20KB)
    _Float16* Hs16 = (_Float16*)&lds[1][0];   // [256][24] f16 (12KB)
    float*    Hs32 = (float*)&lds[1][0];      // [256][20] f32 (20KB)
    {   // stage c tile: 2 thr/row, 2 float4 each (16 units)
        const int bl = t >> 1;
        const int j0 = (t & 1) * 2;
#pragma unroll
        for (int j = 0; j < 2; j++) {
            floatx4 cv = *(const floatx4*)(c_in + (size_t)(n0 + bl) * LSTM_N
                                           + u0 + (j0 + j) * 4);
            *(floatx4*)(Cs + bl * 20 + (j0 + j) * 4) = cv;
        }
    }
    __syncthreads();

#pragma unroll
    for (int mt = 0; mt < 2; mt++) {
        const int ul = (wm >> 2) + mt * 4 + quad;   // 0..15 local unit
        const int u  = u0 + ul;
        const float bi  = bias[u];
        const float bff = bias[400 + u];
        const float bg  = bias[800 + u];
        const float bo  = bias[1200 + u];
#pragma unroll
        for (int nt = 0; nt < 4; nt++) {
            const int bl = wn + nt * 16 + l16;      // local batch 0..255
            float gi = acc[mt][nt][0] + bi;
            float gf = acc[mt][nt][1] + bff;
            float gg = acc[mt][nt][2] + bg;
            float go = acc[mt][nt][3] + bo;
            float si = 1.f / (1.f + expf(-gi));
            float sf = 1.f / (1.f + expf(-gf));
            float so = 1.f / (1.f + expf(-go));
            float cn = sf * Cs[bl * 20 + ul] + si * tanhf(gg);
            float h  = so * tanhf(cn);
            if (fout) Hs32[bl * 20 + ul] = h;
            else      Hs16[bl * 24 + ul] = (_Float16)h;
        }
    }
    __syncthreads();

    if (fout) {   // fp32 out: 64B per batch row, 2 thr/row x 2 float4
        const int bl = t >> 1;
        const int p0 = (t & 1) * 2;
#pragma unroll
        for (int j = 0; j < 2; j++) {
            floatx4 hvv = *(const floatx4*)(Hs32 + bl * 20 + (p0 + j) * 4);
            *(floatx4*)(fout + (size_t)(n0 + bl) * LSTM_N + u0 + (p0 + j) * 4) = hvv;
        }
    } else {      // fp16: 2 thr/row x 1 half8 per dest
        const int bl = t >> 1;
        const int p  = t & 1;
        half8 hvv = *(const half8*)(Hs16 + bl * 24 + p * 8);
        *(half8*)(d1 + (size_t)(n0 + bl) * ld1 + u0 + p * 8) = hvv;
        if (d2) *(half8*)(d2 + (size_t)(n0 + bl) * ld2 + u0 + p * 8) = hvv;
    }
}

// ---------------------------------------------------------------- attn (fused)
// wave = one batch row; 4 waves/block; grid B/4. (Unchanged.)
__global__ __launch_bounds__(256) void attn_fused(const _Float16* __restrict__ Wa,
                                                  const _Float16* __restrict__ XA,
                                                  const float* __restrict__ b_attn,
                                                  const float* __restrict__ kappa,
                                                  const float* __restrict__ AV,
                                                  const int* __restrict__ alen,
                                                  _Float16* __restrict__ X2,
                                                  _Float16* __restrict__ X3)
{
    __shared__ _Float16 Wa_s[30 * KP1];     // 30 KB
    __shared__ float prm[4][32];
    __shared__ float phi_s[4][CHARLEN];

    const int t = threadIdx.x;
#pragma unroll
    for (int i = 0; i < 8; i++) {
        const int idx = t + i * 256;
        if (idx < 1920) {
            const int row = idx >> 6;
            const int c8  = (idx & 63) << 3;
            *(half8*)(&Wa_s[row * KP1 + c8]) = *(const half8*)(Wa + (size_t)row * KP1 + c8);
        }
    }
    __syncthreads();

    const int wave = t >> 6;
    const int lane = t & 63;
    const int b = blockIdx.x * 4 + wave;

    half8 xa = *(const half8*)(XA + (size_t)b * KP1 + lane * 8);
    float xf[8];
#pragma unroll
    for (int e = 0; e < 8; e++) xf[e] = (float)xa[e];

    float myp = 0.f;
#pragma unroll
    for (int m = 0; m < 30; m++) {
        half8 wv = *(const half8*)(&Wa_s[m * KP1 + lane * 8]);
        float s = 0.f;
#pragma unroll
        for (int e = 0; e < 8; e++) s += (float)wv[e] * xf[e];
#pragma unroll
        for (int sh = 32; sh >= 1; sh >>= 1) s += __shfl_xor(s, sh, 64);
        if (lane == m) myp = s;
    }

    if (lane < 30) {
        float p  = myp + b_attn[lane];
        float sp = (p > 20.f) ? p : log1pf(expf(p));
        float v;
        if (lane < 10)      v = sp;
        else if (lane < 20) v = fmaxf(sp, 0.01f);
        else                v = kappa[(size_t)b * NATTN + (lane - 20)] + sp * (1.f / 25.f);
        prm[wave][lane] = v;
    }
    __syncthreads();

    const int len = alen[b];
    {
        int c = lane;
        float phi = 0.f;
#pragma unroll
        for (int j = 0; j < NATTN; j++) {
            float d = prm[wave][20 + j] - (float)c;
            phi += prm[wave][j] * expf(-d * d / prm[wave][10 + j]);
        }
        phi_s[wave][c] = (c < len) ? phi : 0.f;
    }
    __syncthreads();

    for (int v0 = 0; v0 < VOCAB; v0 += 64) {
        const int v = v0 + lane;
        if (v < VOCAB) {
            const float* avb = AV + (size_t)b * CHARLEN * VOCAB + v;
            float s = 0.f;
            for (int c = 0; c < len; c++)
                s += phi_s[wave][c] * avb[(size_t)c * VOCAB];
            _Float16 wv = (_Float16)s;
            X2[(size_t)b * KP23 + 403 + v] = wv;
            X3[(size_t)b * KP23 + 403 + v] = wv;
        }
    }
}

// ---------------------------------------------------------------- launch
extern "C" void kernel_launch(void* const* d_in, const int* in_sizes, int n_in,
                              void* d_out, int out_size, void* d_ws, size_t ws_size,
                              hipStream_t stream)
{
    const float* inputs = (const float*)d_in[0];
    const float* h1     = (const float*)d_in[1];
    const float* c1     = (const float*)d_in[2];
    const float* h2     = (const float*)d_in[3];
    const float* c2     = (const float*)d_in[4];
    const float* h3     = (const float*)d_in[5];
    const float* c3     = (const float*)d_in[6];
    const float* kappa  = (const float*)d_in[7];
    const float* w_prev = (const float*)d_in[8];
    const float* AV     = (const float*)d_in[9];
    const int*   alen   = (const int*)d_in[10];
    const float* W_ih1  = (const float*)d_in[11];
    const float* W_hh1  = (const float*)d_in[12];
    const float* b1     = (const float*)d_in[13];
    const float* W_attn = (const float*)d_in[14];
    const float* b_attn = (const float*)d_in[15];
    const float* W_ih2  = (const float*)d_in[16];
    const float* W_hh2  = (const float*)d_in[17];
    const float* b2     = (const float*)d_in[18];
    const float* W_ih3  = (const float*)d_in[19];
    const float* W_hh3  = (const float*)d_in[20];
    const float* b3     = (const float*)d_in[21];
    float* out = (float*)d_out;

    char* p = (char*)d_ws;
    _Float16* X1 = (_Float16*)p; p += (size_t)B_SZ * KP1 * 2;
    _Float16* XA = (_Float16*)p; p += (size_t)B_SZ * KP1 * 2;
    _Float16* X2 = (_Float16*)p; p += (size_t)B_SZ * KP23 * 2;
    _Float16* X3 = (_Float16*)p; p += (size_t)B_SZ * KP23 * 2;
    _Float16* W1 = (_Float16*)p; p += (size_t)NG * KP1 * 2;
    _Float16* W2 = (_Float16*)p; p += (size_t)NG * KP23 * 2;
    _Float16* W3 = (_Float16*)p; p += (size_t)NG * KP23 * 2;
    _Float16* Wa = (_Float16*)p; p += (size_t)64 * KP1 * 2;

    pack_all<<<O7 / 256, 256, 0, stream>>>(W_ih1, W_hh1, W_ih2, W_hh2,
                                           W_ih3, W_hh3, W_attn,
                                           w_prev, inputs, h1, h2, h3,
                                           W1, W2, W3, Wa, X1, XA, X2, X3);

    const dim3 fgrid(16, 25);   // 400 blocks = 8 XCD x 50

    // LSTM1: h1n -> XA col 0 (attn input) + X2 col 0
    gemm_fused_t<KP1><<<fgrid, 512, 0, stream>>>(W1, X1, b1, c1,
                                                 XA, KP1, X2, KP23, nullptr);
    // attention: params (wave-dot GEMM) + phi + einsum -> w into X2, X3
    attn_fused<<<B_SZ / 4, 256, 0, stream>>>(Wa, XA, b_attn, kappa, AV, alen, X2, X3);
    // LSTM2: h2n -> X3 col 0
    gemm_fused_t<KP23><<<fgrid, 512, 0, stream>>>(W2, X2, b2, c2,
                                                  X3, KP23, nullptr, 0, nullptr);
    // LSTM3: h3n -> out (fp32)
    gemm_fused_t<KP23><<<fgrid, 512, 0, stream>>>(W3, X3, b3, c3,
                                                  nullptr, 0, nullptr, 0, out);
}

// Round 10
// 288.267 us; speedup vs baseline: 1.0129x; 1.0129x over previous
//
#include <hip/hip_runtime.h>
#include <hip/hip_bf16.h>

// Round 18: staging-bytes attack via balanced tile (R8 best=282 kept as base).
//   total staged = M*N*K*2*(1/Mt + 1/Nt); 64x256 -> 0.0195, 160x128 -> 0.0141
//   - 160x128 tile, BK=64, 512 thr = 8 waves (2m x 4n), wave = 80x32 rows
//     (acc[5][2], 20 MFMAs/K-step, +25% per barrier vs R8)
//   - dbuf 2x36KB = 72KB -> 2 blocks/CU = 16 waves/CU (same TLP as R8)
//   - X re-reads 25 -> 10 (183 -> 73MB), total 229 -> 165MB per gemm896
//   - 1600/160 = 10 row-tiles exactly: no M padding; grid 320 = 8 XCD x 40,
//     all blocks co-resident; per-XCD set W 2.9 + X-slice 0.9 < 4MB L2
//   - XOR-swizzle staging/read scheme identical to R8 (proven)
//   - same K-accumulation order -> absmax unchanged

#define B_SZ     4096
#define LSTM_N   400
#define NG       1600   // 4*LSTM
#define VOCAB    73
#define NATTN    10
#define CHARLEN  64
#define KP1      512
#define KP23     896

typedef _Float16 half8 __attribute__((ext_vector_type(8)));
typedef __attribute__((ext_vector_type(4))) float floatx4;

__device__ __forceinline__ void gload_lds16(const void* g, void* l) {
    __builtin_amdgcn_global_load_lds(
        (const __attribute__((address_space(1))) void*)g,
        (__attribute__((address_space(3))) void*)l, 16, 0, 0);
}

// [row][64-half] LDS tile, XOR-swizzled 16B granules within each 128B row
__device__ __forceinline__ int lds_off(int r, int g) {
    return (r << 6) + ((((g ^ r) & 7)) << 3);
}

// ---------------------------------------------------------------- pack (all)
// Layouts:
//   X1 (KP1):  [w_prev 0..73 | inputs 73..76 | h1 76..476 | 0pad]
//   XA (KP1):  [h1n 0..400 | w_prev 400..473 | inputs 473..476 | 0pad]
//   X2 (KP23): [h1n 0..400 | inputs 400..403 | w 403..476 | h2 476..876 | 0pad]
//   X3 (KP23): [h2n 0..400 | inputs 400..403 | w 403..476 | h3 476..876 | 0pad]
// W rows: n = 4u+g <- src row g*400+u.
#define CW1   102400            // 1600 * 64
#define CW23  179200            // 1600 * 112
#define CWA   4096              // 64 * 64
#define CX1   262144            // 4096 * 64
#define CXA   57344             // 4096 * 14   (cols 400..512)
#define CX23  253952            // 4096 * 62   (cols 400..896, both X2 & X3)
#define O1    (CW1)
#define O2    (O1 + CW23)
#define O3    (O2 + CW23)
#define O4    (O3 + CWA)
#define O5    (O4 + CX1)
#define O6    (O5 + CXA)
#define O7    (O6 + CX23)       // 1038336 = 256 * 4056

__global__ __launch_bounds__(256) void pack_all(const float* __restrict__ Wih1,
                                                const float* __restrict__ Whh1,
                                                const float* __restrict__ Wih2,
                                                const float* __restrict__ Whh2,
                                                const float* __restrict__ Wih3,
                                                const float* __restrict__ Whh3,
                                                const float* __restrict__ W_attn,
                                                const float* __restrict__ w_prev,
                                                const float* __restrict__ inputs,
                                                const float* __restrict__ h1,
                                                const float* __restrict__ h2,
                                                const float* __restrict__ h3,
                                                _Float16* __restrict__ W1,
                                                _Float16* __restrict__ W2,
                                                _Float16* __restrict__ W3,
                                                _Float16* __restrict__ Wa,
                                                _Float16* __restrict__ X1,
                                                _Float16* __restrict__ XA,
                                                _Float16* __restrict__ X2,
                                                _Float16* __restrict__ X3)
{
    const int id = blockIdx.x * 256 + threadIdx.x;
    half8 hv;

    if (id < O1) {                       // ---- W1: 1600 x 512
        const int row = id >> 6;
        const int k0  = (id & 63) << 3;
        const int u = row >> 2, g = row & 3;
        const int src = g * 400 + u;
#pragma unroll
        for (int e = 0; e < 8; e++) {
            const int k = k0 + e;
            float x = 0.f;
            if (k < 76)           x = Wih1[(size_t)src * 76 + k];
            else if (k < 476)     x = Whh1[(size_t)src * 400 + (k - 76)];
            hv[e] = (_Float16)x;
        }
        *(half8*)(W1 + (size_t)row * KP1 + k0) = hv;
    } else if (id < O3) {                // ---- W2 / W3: 1600 x 896
        const int id2 = id - O1;
        const bool is3 = (id2 >= CW23);
        const int id3 = is3 ? id2 - CW23 : id2;
        const int row = id3 / 112;
        const int k0  = (id3 - row * 112) << 3;
        const int u = row >> 2, g = row & 3;
        const int src = g * 400 + u;
        const float* Wih = is3 ? Wih3 : Wih2;
        const float* Whh = is3 ? Whh3 : Whh2;
#pragma unroll
        for (int e = 0; e < 8; e++) {
            const int k = k0 + e;
            float x = 0.f;
            if (k < 400)          x = Wih[(size_t)src * 476 + 3 + k];
            else if (k < 403)     x = Wih[(size_t)src * 476 + (k - 400)];
            else if (k < 476)     x = Wih[(size_t)src * 476 + k];
            else if (k < 876)     x = Whh[(size_t)src * 400 + (k - 476)];
            hv[e] = (_Float16)x;
        }
        *(half8*)((is3 ? W3 : W2) + (size_t)row * KP23 + k0) = hv;
    } else if (id < O4) {                // ---- Wa: 64 x 512 (rows >=30 zero)
        const int id4 = id - O3;
        const int row = id4 >> 6;
        const int k0  = (id4 & 63) << 3;
#pragma unroll
        for (int e = 0; e < 8; e++) {
            const int k = k0 + e;
            float x = 0.f;
            if (row < 30) {
                if (k < 400)      x = W_attn[(size_t)row * 476 + 76 + k];
                else if (k < 473) x = W_attn[(size_t)row * 476 + (k - 400)];
                else if (k < 476) x = W_attn[(size_t)row * 476 + 73 + (k - 473)];
            }
            hv[e] = (_Float16)x;
        }
        *(half8*)(Wa + (size_t)row * KP1 + k0) = hv;
    } else if (id < O5) {                // ---- X1: 4096 x 512
        const int id5 = id - O4;
        const int b  = id5 >> 6;
        const int k0 = (id5 & 63) << 3;
#pragma unroll
        for (int e = 0; e < 8; e++) {
            const int k = k0 + e;
            float x = 0.f;
            if (k < 73)           x = w_prev[(size_t)b * 73 + k];
            else if (k < 76)      x = inputs[(size_t)b * 3 + (k - 73)];
            else if (k < 476)     x = h1[(size_t)b * 400 + (k - 76)];
            hv[e] = (_Float16)x;
        }
        *(half8*)(X1 + (size_t)b * KP1 + k0) = hv;
    } else if (id < O6) {                // ---- XA cols 400..512
        const int id6 = id - O5;
        const int b  = id6 / 14;
        const int k0 = 400 + ((id6 - b * 14) << 3);
#pragma unroll
        for (int e = 0; e < 8; e++) {
            const int k = k0 + e;
            float x = 0.f;
            if (k < 473)          x = w_prev[(size_t)b * 73 + (k - 400)];
            else if (k < 476)     x = inputs[(size_t)b * 3 + (k - 473)];
            hv[e] = (_Float16)x;
        }
        *(half8*)(XA + (size_t)b * KP1 + k0) = hv;
    } else if (id < O7) {                // ---- X2+X3 cols 400..896
        const int id7 = id - O6;
        const int b  = id7 / 62;
        const int k0 = 400 + ((id7 - b * 62) << 3);
        half8 h2v, h3v;
#pragma unroll
        for (int e = 0; e < 8; e++) {
            const int k = k0 + e;
            float x2 = 0.f, x3 = 0.f;
            if (k < 403)                    { x2 = inputs[(size_t)b * 3 + (k - 400)]; x3 = x2; }
            else if (k >= 476 && k < 876)   { x2 = h2[(size_t)b * 400 + (k - 476)];
                                              x3 = h3[(size_t)b * 400 + (k - 476)]; }
            h2v[e] = (_Float16)x2;
            h3v[e] = (_Float16)x3;
        }
        *(half8*)(X2 + (size_t)b * KP23 + k0) = h2v;
        *(half8*)(X3 + (size_t)b * KP23 + k0) = h3v;
    }
}

// ---------------------------------------------------------------- fused GEMM
// 160(rows) x 128(batch) tile, BK=64, 512 thr = 8 waves (2m x 4n), each wave
// 80x32 = 5x2 frags, 20 MFMAs/K-step. Dbuf 2x36KB = 72KB -> 2 blocks/CU.
// A = 20 8-row chunks (waves stage 2 each + waves 0-3 one extra);
// B = 16 8-row chunks (2/wave). vmcnt(5) waves 0-3, vmcnt(4) waves 4-7.
template<int KP>
__global__ __launch_bounds__(512, 4) void gemm_fused_t(const _Float16* __restrict__ Wm,
                                                       const _Float16* __restrict__ X,
                                                       const float* __restrict__ bias,
                                                       const float* __restrict__ c_in,
                                                       _Float16* __restrict__ d1, int ld1,
                                                       _Float16* __restrict__ d2, int ld2,
                                                       float* __restrict__ fout)
{
    __shared__ _Float16 lds[2][288 * 64];   // [A 160 rows | B 128 rows] x2 = 72KB

    const int t    = threadIdx.x;
    const int w    = t >> 6;                // 0..7
    const int lane = t & 63;
    const int quad = lane >> 4;
    const int l16  = lane & 15;
    // bijective XCD chunks: 320 = 8 x 40; each XCD: 4 batch-tiles x 10 rows
    const int fid  = blockIdx.y * 32 + blockIdx.x;
    const int xcd  = fid & 7;
    const int loc  = fid >> 3;              // 0..39
    const int bx   = xcd * 4 + loc / 10;    // batch tile 0..31
    const int by   = loc % 10;              // row tile 0..9
    const int m0   = by * 160;
    const int n0   = bx * 128;
    const int wm   = (w >> 2) * 80;         // 0 or 80
    const int wn   = (w & 3) * 32;          // 0,32,64,96
    const int lr   = lane >> 3;             // 0..7 row-in-8
    const int gq   = (lane & 7) ^ lr;       // XOR-swizzled granule (R8 scheme)

    floatx4 acc[5][2] = {};

    auto stage = [&](int sb, int k0) {
        // A: chunks {2w, 2w+1} for all waves; waves 0-3 also chunk 16+w
#pragma unroll
        for (int s = 0; s < 2; s++) {
            const int c = w * 2 + s;
            gload_lds16(Wm + (size_t)(m0 + c * 8 + lr) * KP + k0 + gq * 8,
                        &lds[sb][(c * 8) * 64]);
        }
        if (w < 4) {
            const int c = 16 + w;
            gload_lds16(Wm + (size_t)(m0 + c * 8 + lr) * KP + k0 + gq * 8,
                        &lds[sb][(c * 8) * 64]);
        }
        // B: chunks {2w, 2w+1}
#pragma unroll
        for (int s = 0; s < 2; s++) {
            const int c = w * 2 + s;
            gload_lds16(X + (size_t)(n0 + c * 8 + lr) * KP + k0 + gq * 8,
                        &lds[sb][(160 + c * 8) * 64]);
        }
    };

    stage(0, 0);
    constexpr int NT = KP / 64;
#pragma unroll
    for (int kt = 0; kt < NT; kt++) {
        const int sb = kt & 1;
        if (kt + 1 < NT) {
            stage(sb ^ 1, (kt + 1) * 64);
            if (w < 4) asm volatile("s_waitcnt vmcnt(5)" ::: "memory");
            else       asm volatile("s_waitcnt vmcnt(4)" ::: "memory");
        } else {
            asm volatile("s_waitcnt vmcnt(0)" ::: "memory");
        }
        __builtin_amdgcn_s_barrier();
        __builtin_amdgcn_sched_barrier(0);

#pragma unroll
        for (int h = 0; h < 2; h++) {
            half8 af[5], bf[2];
#pragma unroll
            for (int i = 0; i < 5; i++)
                af[i] = *(const half8*)(&lds[sb][lds_off(wm + i * 16 + l16, h * 4 + quad)]);
#pragma unroll
            for (int i = 0; i < 2; i++)
                bf[i] = *(const half8*)(&lds[sb][lds_off(160 + wn + i * 16 + l16, h * 4 + quad)]);
            __builtin_amdgcn_s_setprio(1);
#pragma unroll
            for (int mt = 0; mt < 5; mt++)
#pragma unroll
                for (int nt = 0; nt < 2; nt++)
                    acc[mt][nt] = __builtin_amdgcn_mfma_f32_16x16x32_f16(
                        af[mt], bf[nt], acc[mt][nt], 0, 0, 0);
            __builtin_amdgcn_s_setprio(0);
        }
        __builtin_amdgcn_s_barrier();
    }
    __builtin_amdgcn_sched_barrier(0);

    // ---------------- epilogue: descattered I/O via LDS transpose ----------
    // Block covers 40 units (u0..u0+39), 128 batch rows. Cs/Hs32 stride 44,
    // Hs16 stride 40 (16B-aligned chunk reads).
    const int u0 = m0 >> 2;                   // by*40
    float*    Cs   = (float*)&lds[0][0];      // [128][44] f32 (22.5KB)
    _Float16* Hs16 = (_Float16*)&lds[1][0];   // [128][40] f16 (10.2KB)
    float*    Hs32 = (float*)&lds[1][0];      // [128][44] f32 (22.5KB)
    {   // stage c tile: 4 thr/row, 10 float4 chunks per row
        const int bl = t >> 2;
        const int p  = t & 3;
#pragma unroll
        for (int j = 0; j < 2; j++) {
            const int ch = p + j * 4;
            floatx4 cv = *(const floatx4*)(c_in + (size_t)(n0 + bl) * LSTM_N + u0 + ch * 4);
            *(floatx4*)(Cs + bl * 44 + ch * 4) = cv;
        }
        if (p < 2) {
            const int ch = 8 + p;
            floatx4 cv = *(const floatx4*)(c_in + (size_t)(n0 + bl) * LSTM_N + u0 + ch * 4);
            *(floatx4*)(Cs + bl * 44 + ch * 4) = cv;
        }
    }
    __syncthreads();

#pragma unroll
    for (int mt = 0; mt < 5; mt++) {
        const int ul = (wm >> 2) + mt * 4 + quad;   // 0..39 local unit
        const int u  = u0 + ul;                     // < 400 always (no pad)
        const float bi  = bias[u];
        const float bff = bias[400 + u];
        const float bg  = bias[800 + u];
        const float bo  = bias[1200 + u];
#pragma unroll
        for (int nt = 0; nt < 2; nt++) {
            const int bl = wn + nt * 16 + l16;      // local batch 0..127
            float gi = acc[mt][nt][0] + bi;
            float gf = acc[mt][nt][1] + bff;
            float gg = acc[mt][nt][2] + bg;
            float go = acc[mt][nt][3] + bo;
            float si = 1.f / (1.f + expf(-gi));
            float sf = 1.f / (1.f + expf(-gf));
            float so = 1.f / (1.f + expf(-go));
            float cn = sf * Cs[bl * 44 + ul] + si * tanhf(gg);
            float h  = so * tanhf(cn);
            if (fout) Hs32[bl * 44 + ul] = h;
            else      Hs16[bl * 40 + ul] = (_Float16)h;
        }
    }
    __syncthreads();

    if (fout) {   // fp32 out: 160B per batch row = 10 float4 chunks
        const int bl = t >> 2;
        const int p  = t & 3;
#pragma unroll
        for (int j = 0; j < 2; j++) {
            const int ch = p + j * 4;
            *(floatx4*)(fout + (size_t)(n0 + bl) * LSTM_N + u0 + ch * 4) =
                *(const floatx4*)(Hs32 + bl * 44 + ch * 4);
        }
        if (p < 2) {
            const int ch = 8 + p;
            *(floatx4*)(fout + (size_t)(n0 + bl) * LSTM_N + u0 + ch * 4) =
                *(const floatx4*)(Hs32 + bl * 44 + ch * 4);
        }
    } else {      // fp16: 80B per batch row = 5 half8 chunks
        const int bl = t >> 2;
        const int p  = t & 3;
        half8 hv1 = *(const half8*)(Hs16 + bl * 40 + p * 8);
        *(half8*)(d1 + (size_t)(n0 + bl) * ld1 + u0 + p * 8) = hv1;
        if (d2) *(half8*)(d2 + (size_t)(n0 + bl) * ld2 + u0 + p * 8) = hv1;
        if (t < 128) {
            half8 hv2 = *(const half8*)(Hs16 + (size_t)t * 40 + 32);
            *(half8*)(d1 + (size_t)(n0 + t) * ld1 + u0 + 32) = hv2;
            if (d2) *(half8*)(d2 + (size_t)(n0 + t) * ld2 + u0 + 32) = hv2;
        }
    }
}

// ---------------------------------------------------------------- attn (fused)
// wave = one batch row; 4 waves/block; grid B/4. (Unchanged.)
__global__ __launch_bounds__(256) void attn_fused(const _Float16* __restrict__ Wa,
                                                  const _Float16* __restrict__ XA,
                                                  const float* __restrict__ b_attn,
                                                  const float* __restrict__ kappa,
                                                  const float* __restrict__ AV,
                                                  const int* __restrict__ alen,
                                                  _Float16* __restrict__ X2,
                                                  _Float16* __restrict__ X3)
{
    __shared__ _Float16 Wa_s[30 * KP1];     // 30 KB
    __shared__ float prm[4][32];
    __shared__ float phi_s[4][CHARLEN];

    const int t = threadIdx.x;
#pragma unroll
    for (int i = 0; i < 8; i++) {
        const int idx = t + i * 256;
        if (idx < 1920) {
            const int row = idx >> 6;
            const int c8  = (idx & 63) << 3;
            *(half8*)(&Wa_s[row * KP1 + c8]) = *(const half8*)(Wa + (size_t)row * KP1 + c8);
        }
    }
    __syncthreads();

    const int wave = t >> 6;
    const int lane = t & 63;
    const int b = blockIdx.x * 4 + wave;

    half8 xa = *(const half8*)(XA + (size_t)b * KP1 + lane * 8);
    float xf[8];
#pragma unroll
    for (int e = 0; e < 8; e++) xf[e] = (float)xa[e];

    float myp = 0.f;
#pragma unroll
    for (int m = 0; m < 30; m++) {
        half8 wv = *(const half8*)(&Wa_s[m * KP1 + lane * 8]);
        float s = 0.f;
#pragma unroll
        for (int e = 0; e < 8; e++) s += (float)wv[e] * xf[e];
#pragma unroll
        for (int sh = 32; sh >= 1; sh >>= 1) s += __shfl_xor(s, sh, 64);
        if (lane == m) myp = s;
    }

    if (lane < 30) {
        float p  = myp + b_attn[lane];
        float sp = (p > 20.f) ? p : log1pf(expf(p));
        float v;
        if (lane < 10)      v = sp;
        else if (lane < 20) v = fmaxf(sp, 0.01f);
        else                v = kappa[(size_t)b * NATTN + (lane - 20)] + sp * (1.f / 25.f);
        prm[wave][lane] = v;
    }
    __syncthreads();

    const int len = alen[b];
    {
        int c = lane;
        float phi = 0.f;
#pragma unroll
        for (int j = 0; j < NATTN; j++) {
            float d = prm[wave][20 + j] - (float)c;
            phi += prm[wave][j] * expf(-d * d / prm[wave][10 + j]);
        }
        phi_s[wave][c] = (c < len) ? phi : 0.f;
    }
    __syncthreads();

    for (int v0 = 0; v0 < VOCAB; v0 += 64) {
        const int v = v0 + lane;
        if (v < VOCAB) {
            const float* avb = AV + (size_t)b * CHARLEN * VOCAB + v;
            float s = 0.f;
            for (int c = 0; c < len; c++)
                s += phi_s[wave][c] * avb[(size_t)c * VOCAB];
            _Float16 wv = (_Float16)s;
            X2[(size_t)b * KP23 + 403 + v] = wv;
            X3[(size_t)b * KP23 + 403 + v] = wv;
        }
    }
}

// ---------------------------------------------------------------- launch
extern "C" void kernel_launch(void* const* d_in, const int* in_sizes, int n_in,
                              void* d_out, int out_size, void* d_ws, size_t ws_size,
                              hipStream_t stream)
{
    const float* inputs = (const float*)d_in[0];
    const float* h1     = (const float*)d_in[1];
    const float* c1     = (const float*)d_in[2];
    const float* h2     = (const float*)d_in[3];
    const float* c2     = (const float*)d_in[4];
    const float* h3     = (const float*)d_in[5];
    const float* c3     = (const float*)d_in[6];
    const float* kappa  = (const float*)d_in[7];
    const float* w_prev = (const float*)d_in[8];
    const float* AV     = (const float*)d_in[9];
    const int*   alen   = (const int*)d_in[10];
    const float* W_ih1  = (const float*)d_in[11];
    const float* W_hh1  = (const float*)d_in[12];
    const float* b1     = (const float*)d_in[13];
    const float* W_attn = (const float*)d_in[14];
    const float* b_attn = (const float*)d_in[15];
    const float* W_ih2  = (const float*)d_in[16];
    const float* W_hh2  = (const float*)d_in[17];
    const float* b2     = (const float*)d_in[18];
    const float* W_ih3  = (const float*)d_in[19];
    const float* W_hh3  = (const float*)d_in[20];
    const float* b3     = (const float*)d_in[21];
    float* out = (float*)d_out;

    char* p = (char*)d_ws;
    _Float16* X1 = (_Float16*)p; p += (size_t)B_SZ * KP1 * 2;
    _Float16* XA = (_Float16*)p; p += (size_t)B_SZ * KP1 * 2;
    _Float16* X2 = (_Float16*)p; p += (size_t)B_SZ * KP23 * 2;
    _Float16* X3 = (_Float16*)p; p += (size_t)B_SZ * KP23 * 2;
    _Float16* W1 = (_Float16*)p; p += (size_t)NG * KP1 * 2;
    _Float16* W2 = (_Float16*)p; p += (size_t)NG * KP23 * 2;
    _Float16* W3 = (_Float16*)p; p += (size_t)NG * KP23 * 2;
    _Float16* Wa = (_Float16*)p; p += (size_t)64 * KP1 * 2;

    pack_all<<<O7 / 256, 256, 0, stream>>>(W_ih1, W_hh1, W_ih2, W_hh2,
                                           W_ih3, W_hh3, W_attn,
                                           w_prev, inputs, h1, h2, h3,
                                           W1, W2, W3, Wa, X1, XA, X2, X3);

    const dim3 fgrid(32, 10);   // 320 blocks = 8 XCD x 40, all co-resident

    // LSTM1: h1n -> XA col 0 (attn input) + X2 col 0
    gemm_fused_t<KP1><<<fgrid, 512, 0, stream>>>(W1, X1, b1, c1,
                                                 XA, KP1, X2, KP23, nullptr);
    // attention: params (wave-dot GEMM) + phi + einsum -> w into X2, X3
    attn_fused<<<B_SZ / 4, 256, 0, stream>>>(Wa, XA, b_attn, kappa, AV, alen, X2, X3);
    // LSTM2: h2n -> X3 col 0
    gemm_fused_t<KP23><<<fgrid, 512, 0, stream>>>(W2, X2, b2, c2,
                                                  X3, KP23, nullptr, 0, nullptr);
    // LSTM3: h3n -> out (fp32)
    gemm_fused_t<KP23><<<fgrid, 512, 0, stream>>>(W3, X3, b3, c3,
                                                  nullptr, 0, nullptr, 0, out);
}

// Round 11
// 278.667 us; speedup vs baseline: 1.0478x; 1.0344x over previous
//
#include <hip/hip_runtime.h>
#include <hip/hip_bf16.h>

// Round 19: clean 24-waves/CU test at BK=64 (R9's 24-wave try was confounded
// by doubling the barrier rate with BK=32; R8's 8->16 waves was the only win).
//   - 64x128 tile, BK=64, 512 thr = 8 waves (2m x 4n, wave 32x32, 8 MFMA/step)
//   - dbuf 2x24KB = 48KB -> 3 blocks/CU = 24 waves/CU (6 waves/SIMD)
//   - staging uniform 3 loads/thread (1 A chunk + 2 B chunks), vmcnt(3)
//   - grid 800 = 8 XCD x (4 batch-tiles x 25 row-tiles); W+X-slice < 4MB L2
//   - XOR swizzle + K-accumulation order unchanged -> same absmax
//   - pack_all / attn_fused verbatim from R8 (282us best)

#define B_SZ     4096
#define LSTM_N   400
#define NG       1600   // 4*LSTM
#define VOCAB    73
#define NATTN    10
#define CHARLEN  64
#define KP1      512
#define KP23     896

typedef _Float16 half8 __attribute__((ext_vector_type(8)));
typedef __attribute__((ext_vector_type(4))) float floatx4;

__device__ __forceinline__ void gload_lds16(const void* g, void* l) {
    __builtin_amdgcn_global_load_lds(
        (const __attribute__((address_space(1))) void*)g,
        (__attribute__((address_space(3))) void*)l, 16, 0, 0);
}

// [row][64-half] LDS tile, XOR-swizzled 16B granules within each 128B row
__device__ __forceinline__ int lds_off(int r, int g) {
    return (r << 6) + ((((g ^ r) & 7)) << 3);
}

// ---------------------------------------------------------------- pack (all)
// Layouts:
//   X1 (KP1):  [w_prev 0..73 | inputs 73..76 | h1 76..476 | 0pad]
//   XA (KP1):  [h1n 0..400 | w_prev 400..473 | inputs 473..476 | 0pad]
//   X2 (KP23): [h1n 0..400 | inputs 400..403 | w 403..476 | h2 476..876 | 0pad]
//   X3 (KP23): [h2n 0..400 | inputs 400..403 | w 403..476 | h3 476..876 | 0pad]
// W rows: n = 4u+g <- src row g*400+u.
#define CW1   102400            // 1600 * 64
#define CW23  179200            // 1600 * 112
#define CWA   4096              // 64 * 64
#define CX1   262144            // 4096 * 64
#define CXA   57344             // 4096 * 14   (cols 400..512)
#define CX23  253952            // 4096 * 62   (cols 400..896, both X2 & X3)
#define O1    (CW1)
#define O2    (O1 + CW23)
#define O3    (O2 + CW23)
#define O4    (O3 + CWA)
#define O5    (O4 + CX1)
#define O6    (O5 + CXA)
#define O7    (O6 + CX23)       // 1038336 = 256 * 4056

__global__ __launch_bounds__(256) void pack_all(const float* __restrict__ Wih1,
                                                const float* __restrict__ Whh1,
                                                const float* __restrict__ Wih2,
                                                const float* __restrict__ Whh2,
                                                const float* __restrict__ Wih3,
                                                const float* __restrict__ Whh3,
                                                const float* __restrict__ W_attn,
                                                const float* __restrict__ w_prev,
                                                const float* __restrict__ inputs,
                                                const float* __restrict__ h1,
                                                const float* __restrict__ h2,
                                                const float* __restrict__ h3,
                                                _Float16* __restrict__ W1,
                                                _Float16* __restrict__ W2,
                                                _Float16* __restrict__ W3,
                                                _Float16* __restrict__ Wa,
                                                _Float16* __restrict__ X1,
                                                _Float16* __restrict__ XA,
                                                _Float16* __restrict__ X2,
                                                _Float16* __restrict__ X3)
{
    const int id = blockIdx.x * 256 + threadIdx.x;
    half8 hv;

    if (id < O1) {                       // ---- W1: 1600 x 512
        const int row = id >> 6;
        const int k0  = (id & 63) << 3;
        const int u = row >> 2, g = row & 3;
        const int src = g * 400 + u;
#pragma unroll
        for (int e = 0; e < 8; e++) {
            const int k = k0 + e;
            float x = 0.f;
            if (k < 76)           x = Wih1[(size_t)src * 76 + k];
            else if (k < 476)     x = Whh1[(size_t)src * 400 + (k - 76)];
            hv[e] = (_Float16)x;
        }
        *(half8*)(W1 + (size_t)row * KP1 + k0) = hv;
    } else if (id < O3) {                // ---- W2 / W3: 1600 x 896
        const int id2 = id - O1;
        const bool is3 = (id2 >= CW23);
        const int id3 = is3 ? id2 - CW23 : id2;
        const int row = id3 / 112;
        const int k0  = (id3 - row * 112) << 3;
        const int u = row >> 2, g = row & 3;
        const int src = g * 400 + u;
        const float* Wih = is3 ? Wih3 : Wih2;
        const float* Whh = is3 ? Whh3 : Whh2;
#pragma unroll
        for (int e = 0; e < 8; e++) {
            const int k = k0 + e;
            float x = 0.f;
            if (k < 400)          x = Wih[(size_t)src * 476 + 3 + k];
            else if (k < 403)     x = Wih[(size_t)src * 476 + (k - 400)];
            else if (k < 476)     x = Wih[(size_t)src * 476 + k];
            else if (k < 876)     x = Whh[(size_t)src * 400 + (k - 476)];
            hv[e] = (_Float16)x;
        }
        *(half8*)((is3 ? W3 : W2) + (size_t)row * KP23 + k0) = hv;
    } else if (id < O4) {                // ---- Wa: 64 x 512 (rows >=30 zero)
        const int id4 = id - O3;
        const int row = id4 >> 6;
        const int k0  = (id4 & 63) << 3;
#pragma unroll
        for (int e = 0; e < 8; e++) {
            const int k = k0 + e;
            float x = 0.f;
            if (row < 30) {
                if (k < 400)      x = W_attn[(size_t)row * 476 + 76 + k];
                else if (k < 473) x = W_attn[(size_t)row * 476 + (k - 400)];
                else if (k < 476) x = W_attn[(size_t)row * 476 + 73 + (k - 473)];
            }
            hv[e] = (_Float16)x;
        }
        *(half8*)(Wa + (size_t)row * KP1 + k0) = hv;
    } else if (id < O5) {                // ---- X1: 4096 x 512
        const int id5 = id - O4;
        const int b  = id5 >> 6;
        const int k0 = (id5 & 63) << 3;
#pragma unroll
        for (int e = 0; e < 8; e++) {
            const int k = k0 + e;
            float x = 0.f;
            if (k < 73)           x = w_prev[(size_t)b * 73 + k];
            else if (k < 76)      x = inputs[(size_t)b * 3 + (k - 73)];
            else if (k < 476)     x = h1[(size_t)b * 400 + (k - 76)];
            hv[e] = (_Float16)x;
        }
        *(half8*)(X1 + (size_t)b * KP1 + k0) = hv;
    } else if (id < O6) {                // ---- XA cols 400..512
        const int id6 = id - O5;
        const int b  = id6 / 14;
        const int k0 = 400 + ((id6 - b * 14) << 3);
#pragma unroll
        for (int e = 0; e < 8; e++) {
            const int k = k0 + e;
            float x = 0.f;
            if (k < 473)          x = w_prev[(size_t)b * 73 + (k - 400)];
            else if (k < 476)     x = inputs[(size_t)b * 3 + (k - 473)];
            hv[e] = (_Float16)x;
        }
        *(half8*)(XA + (size_t)b * KP1 + k0) = hv;
    } else if (id < O7) {                // ---- X2+X3 cols 400..896
        const int id7 = id - O6;
        const int b  = id7 / 62;
        const int k0 = 400 + ((id7 - b * 62) << 3);
        half8 h2v, h3v;
#pragma unroll
        for (int e = 0; e < 8; e++) {
            const int k = k0 + e;
            float x2 = 0.f, x3 = 0.f;
            if (k < 403)                    { x2 = inputs[(size_t)b * 3 + (k - 400)]; x3 = x2; }
            else if (k >= 476 && k < 876)   { x2 = h2[(size_t)b * 400 + (k - 476)];
                                              x3 = h3[(size_t)b * 400 + (k - 476)]; }
            h2v[e] = (_Float16)x2;
            h3v[e] = (_Float16)x3;
        }
        *(half8*)(X2 + (size_t)b * KP23 + k0) = h2v;
        *(half8*)(X3 + (size_t)b * KP23 + k0) = h3v;
    }
}

// ---------------------------------------------------------------- fused GEMM
// 64(rows) x 128(batch) tile, BK=64, 512 thr = 8 waves (2m x 4n), wave 32x32
// (acc[2][2], 8 MFMAs/K-step). Dbuf 2x24KB = 48KB -> 3 blocks/CU =
// 24 waves/CU. Staging uniform 3 loads/thread: A chunk w, B chunks 2w,2w+1.
template<int KP>
__global__ __launch_bounds__(512, 6) void gemm_fused_t(const _Float16* __restrict__ Wm,
                                                       const _Float16* __restrict__ X,
                                                       const float* __restrict__ bias,
                                                       const float* __restrict__ c_in,
                                                       _Float16* __restrict__ d1, int ld1,
                                                       _Float16* __restrict__ d2, int ld2,
                                                       float* __restrict__ fout)
{
    __shared__ _Float16 lds[2][192 * 64];   // [A 64 rows | B 128 rows] x2 = 48KB

    const int t    = threadIdx.x;
    const int w    = t >> 6;                // 0..7
    const int lane = t & 63;
    const int quad = lane >> 4;
    const int l16  = lane & 15;
    // bijective XCD chunks: 800 = 8 x 100; each XCD: 4 batch-tiles x 25 rows
    const int fid  = blockIdx.y * 32 + blockIdx.x;
    const int xcd  = fid & 7;
    const int loc  = fid >> 3;              // 0..99
    const int bx   = xcd * 4 + loc / 25;    // batch tile 0..31
    const int by   = loc % 25;              // row tile 0..24
    const int m0   = by * 64;
    const int n0   = bx * 128;
    const int wm   = (w >> 2) * 32;         // 0 or 32
    const int wn   = (w & 3) * 32;          // 0,32,64,96
    const int lr   = lane >> 3;             // 0..7 row-in-8
    const int gq   = (lane & 7) ^ lr;       // XOR-swizzled granule

    floatx4 acc[2][2] = {};

    // uniform 3 loads/thread per K-step: A chunk w, B chunks {2w, 2w+1}
    auto stage = [&](int sb, int k0) {
        gload_lds16(Wm + (size_t)(m0 + w * 8 + lr) * KP + k0 + gq * 8,
                    &lds[sb][(w * 8) * 64]);
#pragma unroll
        for (int s = 0; s < 2; s++) {
            const int c = w * 2 + s;
            gload_lds16(X + (size_t)(n0 + c * 8 + lr) * KP + k0 + gq * 8,
                        &lds[sb][(64 + c * 8) * 64]);
        }
    };

    stage(0, 0);
    constexpr int NT = KP / 64;
#pragma unroll
    for (int kt = 0; kt < NT; kt++) {
        const int sb = kt & 1;
        if (kt + 1 < NT) {
            stage(sb ^ 1, (kt + 1) * 64);
            asm volatile("s_waitcnt vmcnt(3)" ::: "memory");
        } else {
            asm volatile("s_waitcnt vmcnt(0)" ::: "memory");
        }
        __builtin_amdgcn_s_barrier();
        __builtin_amdgcn_sched_barrier(0);

#pragma unroll
        for (int h = 0; h < 2; h++) {
            half8 af[2], bf[2];
#pragma unroll
            for (int i = 0; i < 2; i++)
                af[i] = *(const half8*)(&lds[sb][lds_off(wm + i * 16 + l16, h * 4 + quad)]);
#pragma unroll
            for (int i = 0; i < 2; i++)
                bf[i] = *(const half8*)(&lds[sb][lds_off(64 + wn + i * 16 + l16, h * 4 + quad)]);
            __builtin_amdgcn_s_setprio(1);
#pragma unroll
            for (int mt = 0; mt < 2; mt++)
#pragma unroll
                for (int nt = 0; nt < 2; nt++)
                    acc[mt][nt] = __builtin_amdgcn_mfma_f32_16x16x32_f16(
                        af[mt], bf[nt], acc[mt][nt], 0, 0, 0);
            __builtin_amdgcn_s_setprio(0);
        }
        __builtin_amdgcn_s_barrier();
    }
    __builtin_amdgcn_sched_barrier(0);

    // ---------------- epilogue: descattered I/O via LDS transpose ----------
    // Block: 16 units x 128 batch rows.
    const int u0 = m0 >> 2;
    float*    Cs   = (float*)&lds[0][0];      // [128][20] f32 (10.2KB)
    _Float16* Hs16 = (_Float16*)&lds[1][0];   // [128][24] f16 (6KB)
    float*    Hs32 = (float*)&lds[1][0];      // [128][20] f32 (10.2KB)
    {   // stage c tile: 4 thr/row, 1 float4 each
        const int bl = t >> 2;
        const int p  = t & 3;
        floatx4 cv = *(const floatx4*)(c_in + (size_t)(n0 + bl) * LSTM_N + u0 + p * 4);
        *(floatx4*)(Cs + bl * 20 + p * 4) = cv;
    }
    __syncthreads();

#pragma unroll
    for (int mt = 0; mt < 2; mt++) {
        const int ul = (wm >> 2) + mt * 4 + quad;   // 0..15 local unit
        const int u  = u0 + ul;
        const float bi  = bias[u];
        const float bff = bias[400 + u];
        const float bg  = bias[800 + u];
        const float bo  = bias[1200 + u];
#pragma unroll
        for (int nt = 0; nt < 2; nt++) {
            const int bl = wn + nt * 16 + l16;      // local batch 0..127
            float gi = acc[mt][nt][0] + bi;
            float gf = acc[mt][nt][1] + bff;
            float gg = acc[mt][nt][2] + bg;
            float go = acc[mt][nt][3] + bo;
            float si = 1.f / (1.f + expf(-gi));
            float sf = 1.f / (1.f + expf(-gf));
            float so = 1.f / (1.f + expf(-go));
            float cn = sf * Cs[bl * 20 + ul] + si * tanhf(gg);
            float h  = so * tanhf(cn);
            if (fout) Hs32[bl * 20 + ul] = h;
            else      Hs16[bl * 24 + ul] = (_Float16)h;
        }
    }
    __syncthreads();

    if (fout) {   // fp32: 4 float4 chunks/row x 128 rows = 512, 1/thread
        const int bl = t >> 2;
        const int ch = t & 3;
        *(floatx4*)(fout + (size_t)(n0 + bl) * LSTM_N + u0 + ch * 4) =
            *(const floatx4*)(Hs32 + bl * 20 + ch * 4);
    } else if (t < 256) {   // fp16: 2 half8/row x 128 rows = 256 chunks
        const int bl = t >> 1;
        const int p  = t & 1;
        half8 hvv = *(const half8*)(Hs16 + bl * 24 + p * 8);
        *(half8*)(d1 + (size_t)(n0 + bl) * ld1 + u0 + p * 8) = hvv;
        if (d2) *(half8*)(d2 + (size_t)(n0 + bl) * ld2 + u0 + p * 8) = hvv;
    }
}

// ---------------------------------------------------------------- attn (fused)
// wave = one batch row; 4 waves/block; grid B/4. (Unchanged.)
__global__ __launch_bounds__(256) void attn_fused(const _Float16* __restrict__ Wa,
                                                  const _Float16* __restrict__ XA,
                                                  const float* __restrict__ b_attn,
                                                  const float* __restrict__ kappa,
                                                  const float* __restrict__ AV,
                                                  const int* __restrict__ alen,
                                                  _Float16* __restrict__ X2,
                                                  _Float16* __restrict__ X3)
{
    __shared__ _Float16 Wa_s[30 * KP1];     // 30 KB
    __shared__ float prm[4][32];
    __shared__ float phi_s[4][CHARLEN];

    const int t = threadIdx.x;
#pragma unroll
    for (int i = 0; i < 8; i++) {
        const int idx = t + i * 256;
        if (idx < 1920) {
            const int row = idx >> 6;
            const int c8  = (idx & 63) << 3;
            *(half8*)(&Wa_s[row * KP1 + c8]) = *(const half8*)(Wa + (size_t)row * KP1 + c8);
        }
    }
    __syncthreads();

    const int wave = t >> 6;
    const int lane = t & 63;
    const int b = blockIdx.x * 4 + wave;

    half8 xa = *(const half8*)(XA + (size_t)b * KP1 + lane * 8);
    float xf[8];
#pragma unroll
    for (int e = 0; e < 8; e++) xf[e] = (float)xa[e];

    float myp = 0.f;
#pragma unroll
    for (int m = 0; m < 30; m++) {
        half8 wv = *(const half8*)(&Wa_s[m * KP1 + lane * 8]);
        float s = 0.f;
#pragma unroll
        for (int e = 0; e < 8; e++) s += (float)wv[e] * xf[e];
#pragma unroll
        for (int sh = 32; sh >= 1; sh >>= 1) s += __shfl_xor(s, sh, 64);
        if (lane == m) myp = s;
    }

    if (lane < 30) {
        float p  = myp + b_attn[lane];
        float sp = (p > 20.f) ? p : log1pf(expf(p));
        float v;
        if (lane < 10)      v = sp;
        else if (lane < 20) v = fmaxf(sp, 0.01f);
        else                v = kappa[(size_t)b * NATTN + (lane - 20)] + sp * (1.f / 25.f);
        prm[wave][lane] = v;
    }
    __syncthreads();

    const int len = alen[b];
    {
        int c = lane;
        float phi = 0.f;
#pragma unroll
        for (int j = 0; j < NATTN; j++) {
            float d = prm[wave][20 + j] - (float)c;
            phi += prm[wave][j] * expf(-d * d / prm[wave][10 + j]);
        }
        phi_s[wave][c] = (c < len) ? phi : 0.f;
    }
    __syncthreads();

    for (int v0 = 0; v0 < VOCAB; v0 += 64) {
        const int v = v0 + lane;
        if (v < VOCAB) {
            const float* avb = AV + (size_t)b * CHARLEN * VOCAB + v;
            float s = 0.f;
            for (int c = 0; c < len; c++)
                s += phi_s[wave][c] * avb[(size_t)c * VOCAB];
            _Float16 wv = (_Float16)s;
            X2[(size_t)b * KP23 + 403 + v] = wv;
            X3[(size_t)b * KP23 + 403 + v] = wv;
        }
    }
}

// ---------------------------------------------------------------- launch
extern "C" void kernel_launch(void* const* d_in, const int* in_sizes, int n_in,
                              void* d_out, int out_size, void* d_ws, size_t ws_size,
                              hipStream_t stream)
{
    const float* inputs = (const float*)d_in[0];
    const float* h1     = (const float*)d_in[1];
    const float* c1     = (const float*)d_in[2];
    const float* h2     = (const float*)d_in[3];
    const float* c2     = (const float*)d_in[4];
    const float* h3     = (const float*)d_in[5];
    const float* c3     = (const float*)d_in[6];
    const float* kappa  = (const float*)d_in[7];
    const float* w_prev = (const float*)d_in[8];
    const float* AV     = (const float*)d_in[9];
    const int*   alen   = (const int*)d_in[10];
    const float* W_ih1  = (const float*)d_in[11];
    const float* W_hh1  = (const float*)d_in[12];
    const float* b1     = (const float*)d_in[13];
    const float* W_attn = (const float*)d_in[14];
    const float* b_attn = (const float*)d_in[15];
    const float* W_ih2  = (const float*)d_in[16];
    const float* W_hh2  = (const float*)d_in[17];
    const float* b2     = (const float*)d_in[18];
    const float* W_ih3  = (const float*)d_in[19];
    const float* W_hh3  = (const float*)d_in[20];
    const float* b3     = (const float*)d_in[21];
    float* out = (float*)d_out;

    char* p = (char*)d_ws;
    _Float16* X1 = (_Float16*)p; p += (size_t)B_SZ * KP1 * 2;
    _Float16* XA = (_Float16*)p; p += (size_t)B_SZ * KP1 * 2;
    _Float16* X2 = (_Float16*)p; p += (size_t)B_SZ * KP23 * 2;
    _Float16* X3 = (_Float16*)p; p += (size_t)B_SZ * KP23 * 2;
    _Float16* W1 = (_Float16*)p; p += (size_t)NG * KP1 * 2;
    _Float16* W2 = (_Float16*)p; p += (size_t)NG * KP23 * 2;
    _Float16* W3 = (_Float16*)p; p += (size_t)NG * KP23 * 2;
    _Float16* Wa = (_Float16*)p; p += (size_t)64 * KP1 * 2;

    pack_all<<<O7 / 256, 256, 0, stream>>>(W_ih1, W_hh1, W_ih2, W_hh2,
                                           W_ih3, W_hh3, W_attn,
                                           w_prev, inputs, h1, h2, h3,
                                           W1, W2, W3, Wa, X1, XA, X2, X3);

    const dim3 fgrid(32, 25);   // 800 blocks = 8 XCD x 100

    // LSTM1: h1n -> XA col 0 (attn input) + X2 col 0
    gemm_fused_t<KP1><<<fgrid, 512, 0, stream>>>(W1, X1, b1, c1,
                                                 XA, KP1, X2, KP23, nullptr);
    // attention: params (wave-dot GEMM) + phi + einsum -> w into X2, X3
    attn_fused<<<B_SZ / 4, 256, 0, stream>>>(Wa, XA, b_attn, kappa, AV, alen, X2, X3);
    // LSTM2: h2n -> X3 col 0
    gemm_fused_t<KP23><<<fgrid, 512, 0, stream>>>(W2, X2, b2, c2,
                                                  X3, KP23, nullptr, 0, nullptr);
    // LSTM3: h3n -> out (fp32)
    gemm_fused_t<KP23><<<fgrid, 512, 0, stream>>>(W3, X3, b3, c3,
                                                  nullptr, 0, nullptr, 0, out);
}